// Round 4
// baseline (637.624 us; speedup 1.0000x reference)
//
#include <hip/hip_runtime.h>

// CrossAttention: out = softmax((S2 Wq)(S1 Wk)^T) (S1 Wv) Wo + bo
// Refactored: Wvo = Wv@Wo (512x512);  V'' = S1@Wvo + bo;  out = softmax(QK^T) @ V''
// fp16 MFMA (16x16x32), fp32 accumulate.
// R4: revert R3's pipelined staging (post-timing divergence). Attention uses the
// R2-proven stage->barrier->compute->barrier structure, but with Q-tile 32 and
// 512 blocks -> 2 blocks/CU so the second block's MFMA hides the first block's
// barrier/vmcnt drains (TLP instead of the fragile intra-block ILP).

typedef _Float16 h_t;
typedef _Float16 h8 __attribute__((ext_vector_type(8)));
typedef _Float16 h4 __attribute__((ext_vector_type(4)));
typedef float f4 __attribute__((ext_vector_type(4)));

#define MFMA16(a, b, c) __builtin_amdgcn_mfma_f32_16x16x32_f16(a, b, c, 0, 0, 0)

typedef const __attribute__((address_space(1))) void* gas_t;
typedef __attribute__((address_space(3))) void* las_t;

__device__ __forceinline__ void gl2lds16(const void* g, void* l) {
    __builtin_amdgcn_global_load_lds((gas_t)g, (las_t)l, 16, 0, 0);
}

// ---------------- merged cast fp32 -> fp16: S1, S2, Wv ----------------
__global__ __launch_bounds__(256) void k_cast3(const float* __restrict__ S1,
                                               const float* __restrict__ S2,
                                               const float* __restrict__ Wv,
                                               h_t* __restrict__ S1h,
                                               h_t* __restrict__ S2h,
                                               h_t* __restrict__ Wvh) {
    long i = (long)blockIdx.x * 256 + threadIdx.x;  // f4 index
    const long n = 2097152;                          // S1/S2 f4 count
    const float* src;
    h_t* dst;
    long off;
    if (i < n) { src = S1; dst = S1h; off = i; }
    else if (i < 2 * n) { src = S2; dst = S2h; off = i - n; }
    else { src = Wv; dst = Wvh; off = i - 2 * n; }
    float4 v = *((const float4*)src + off);
    h4 h = {(h_t)v.x, (h_t)v.y, (h_t)v.z, (h_t)v.w};
    *((h4*)dst + off) = h;
}

// ---------------- merged transpose+cast: Wq, Wk, Wo -> [N][K] f16 ----------------
__global__ __launch_bounds__(256) void k_transpose3(const float* __restrict__ Wq,
                                                    const float* __restrict__ Wk,
                                                    const float* __restrict__ Wo,
                                                    h_t* __restrict__ Wqt,
                                                    h_t* __restrict__ Wkt,
                                                    h_t* __restrict__ Wot) {
    const float* in;
    h_t* out;
    int K, N;
    if (blockIdx.z == 0) { in = Wq; out = Wqt; K = 512; N = 1024; }
    else if (blockIdx.z == 1) { in = Wk; out = Wkt; K = 512; N = 1024; }
    else { in = Wo; out = Wot; K = 1024; N = 512; }
    int kb = blockIdx.y * 32, nb = blockIdx.x * 32;
    if (kb >= K || nb >= N) return;
    __shared__ float tile[32][33];
    int x = threadIdx.x & 31, y = threadIdx.x >> 5;
#pragma unroll
    for (int j = 0; j < 4; j++)
        tile[y + j * 8][x] = in[(size_t)(kb + y + j * 8) * N + nb + x];
    __syncthreads();
#pragma unroll
    for (int j = 0; j < 4; j++)
        out[(size_t)(nb + y + j * 8) * K + kb + x] = (h_t)tile[x][y + j * 8];
}

// ---------------- m97-style NT GEMM: C[M][N] f16 = A[M][K] x Bt[N][K]^T ------------
__global__ __launch_bounds__(256) void k_gemm(const h_t* __restrict__ A,
                                              const h_t* __restrict__ Bt,
                                              h_t* __restrict__ C,
                                              int M, int N, int K) {
    __shared__ h_t As[128 * 64];
    __shared__ h_t Bs[128 * 64];
    int t = threadIdx.x, w = t >> 6, lane = t & 63;
    int q16 = lane >> 4, l16 = lane & 15;
    size_t m0 = (size_t)blockIdx.x * 128, n0 = (size_t)blockIdx.y * 128;
    int wr = (w >> 1) * 64, wc = (w & 1) * 64;
    f4 acc[4][4] = {};

    for (int k0 = 0; k0 < K; k0 += 64) {
#pragma unroll
        for (int j = 0; j < 4; j++) {
            int q = w * 4 + j;
            int row = q * 8 + (lane >> 3);
            int ks = (((lane & 7) ^ (row & 7)) << 3);
            gl2lds16(A + (m0 + row) * K + k0 + ks, &As[q * 512]);
            gl2lds16(Bt + (n0 + row) * K + k0 + ks, &Bs[q * 512]);
        }
        __syncthreads();
#pragma unroll
        for (int ks = 0; ks < 2; ks++) {
            h8 av[4], bv[4];
#pragma unroll
            for (int i = 0; i < 4; i++) {
                int row = wr + i * 16 + l16;
                int ch = ks * 4 + q16;
                av[i] = *(const h8*)&As[row * 64 + ((ch ^ (row & 7)) << 3)];
            }
#pragma unroll
            for (int j = 0; j < 4; j++) {
                int row = wc + j * 16 + l16;
                int ch = ks * 4 + q16;
                bv[j] = *(const h8*)&Bs[row * 64 + ((ch ^ (row & 7)) << 3)];
            }
#pragma unroll
            for (int i = 0; i < 4; i++)
#pragma unroll
                for (int j = 0; j < 4; j++)
                    acc[i][j] = MFMA16(av[i], bv[j], acc[i][j]);
        }
        __syncthreads();
    }
#pragma unroll
    for (int i = 0; i < 4; i++) {
        size_t r0 = m0 + wr + i * 16 + q16 * 4;
#pragma unroll
        for (int j = 0; j < 4; j++) {
            size_t c = n0 + wc + j * 16 + l16;
#pragma unroll
            for (int r = 0; r < 4; r++)
                C[(r0 + r) * N + c] = (h_t)acc[i][j][r];
        }
    }
}

// ---------------- V'' GEMM: +bias, transposed store Vt[b][d][n] -------------------
__global__ __launch_bounds__(256) void k_gemm_vt(const h_t* __restrict__ A,
                                                 const h_t* __restrict__ Bt,
                                                 const float* __restrict__ bo,
                                                 h_t* __restrict__ Vt,
                                                 int M, int N, int K) {
    __shared__ h_t As[128 * 64];
    __shared__ h_t Bs[128 * 64];
    int t = threadIdx.x, w = t >> 6, lane = t & 63;
    int q16 = lane >> 4, l16 = lane & 15;
    size_t m0 = (size_t)blockIdx.x * 128, n0 = (size_t)blockIdx.y * 128;
    int wr = (w >> 1) * 64, wc = (w & 1) * 64;
    f4 acc[4][4] = {};

    for (int k0 = 0; k0 < K; k0 += 64) {
#pragma unroll
        for (int j = 0; j < 4; j++) {
            int q = w * 4 + j;
            int row = q * 8 + (lane >> 3);
            int ks = (((lane & 7) ^ (row & 7)) << 3);
            gl2lds16(A + (m0 + row) * K + k0 + ks, &As[q * 512]);
            gl2lds16(Bt + (n0 + row) * K + k0 + ks, &Bs[q * 512]);
        }
        __syncthreads();
#pragma unroll
        for (int ks = 0; ks < 2; ks++) {
            h8 av[4], bv[4];
#pragma unroll
            for (int i = 0; i < 4; i++) {
                int row = wr + i * 16 + l16;
                int ch = ks * 4 + q16;
                av[i] = *(const h8*)&As[row * 64 + ((ch ^ (row & 7)) << 3)];
            }
#pragma unroll
            for (int j = 0; j < 4; j++) {
                int row = wc + j * 16 + l16;
                int ch = ks * 4 + q16;
                bv[j] = *(const h8*)&Bs[row * 64 + ((ch ^ (row & 7)) << 3)];
            }
#pragma unroll
            for (int i = 0; i < 4; i++)
#pragma unroll
                for (int j = 0; j < 4; j++)
                    acc[i][j] = MFMA16(av[i], bv[j], acc[i][j]);
        }
        __syncthreads();
    }
#pragma unroll
    for (int i = 0; i < 4; i++) {
        size_t gm = m0 + wr + i * 16 + q16 * 4;
        size_t b = gm >> 11;
        size_t n = gm & 2047;
#pragma unroll
        for (int j = 0; j < 4; j++) {
            size_t d = n0 + wc + j * 16 + l16;
            float bias = bo[d];
            h4 hv = {(h_t)(acc[i][j][0] + bias), (h_t)(acc[i][j][1] + bias),
                     (h_t)(acc[i][j][2] + bias), (h_t)(acc[i][j][3] + bias)};
            *(h4*)&Vt[(b * 512 + d) * 2048 + n] = hv;
        }
    }
}

// ---------------- fused flash attention (R2 structure, 2 blocks/CU) ----------------
// 512 blocks (2/CU), 512 threads (8 waves = 2 row-bands x 4 col-quarters).
// Q-tile 32 rows, 128-key tiles staged as 4 chunks of 256 (stage->barrier->
// compute->barrier, the R2-proven pattern). LDS ~74 KB -> 2 blocks/CU.
__global__ __launch_bounds__(512) void k_attn(const h_t* __restrict__ Qh,
                                              const h_t* __restrict__ Kh,
                                              const h_t* __restrict__ Vt,
                                              float* __restrict__ Out) {
    __shared__ h_t Ks[128 * 256];     // 64 KB, XOR-swizzled 16B chunks
    __shared__ h_t Ps[32 * 136];      // 8.7 KB probs, padded stride
    __shared__ float Stat[4][32][2];  // per-col-quarter (max, sumexp)
    __shared__ float arow[32];        // broadcast alpha / final l

    int t = threadIdx.x, w = t >> 6, lane = t & 63;
    int q16 = lane >> 4, l16 = lane & 15;
    int rb = w & 1, ch = w >> 1;      // row band (0..1), col quarter (0..3)
    int b = blockIdx.x & 7;
    int q0 = (blockIdx.x >> 3) * 32;

    const h_t* Kbase = Kh + (size_t)b * 2048 * 1024;
    const h_t* Vbase = Vt + (size_t)b * 512 * 2048;

    // Q fragments: rows rb*16+l16, k = f*32 + q16*8 .. +8 (128 VGPR)
    h8 qf[32];
    {
        size_t qrow = (size_t)b * 2048 + q0 + rb * 16 + l16;
        const h_t* qp = Qh + qrow * 1024 + q16 * 8;
#pragma unroll
        for (int f = 0; f < 32; f++) qf[f] = *(const h8*)(qp + f * 32);
    }
    f4 oacc[2][4] = {};
    float mrun[4] = {-1e30f, -1e30f, -1e30f, -1e30f};
    float lrun[4] = {0.f, 0.f, 0.f, 0.f};

    for (int kt = 0; kt < 16; kt++) {
        int kb = kt * 128;
        f4 sacc[2] = {};
        // ---- S = Q K^T over inner 1024, staged in 4 chunks of 256 ----
#pragma unroll
        for (int c4 = 0; c4 < 4; c4++) {
#pragma unroll
            for (int j = 0; j < 8; j++) {
                int qch = w * 8 + j;
                int row = qch * 2 + (lane >> 5);
                int kg = lane & 31;
                gl2lds16(Kbase + (size_t)(kb + row) * 1024 + c4 * 256 +
                             ((kg ^ (row & 7)) << 3),
                         &Ks[qch * 512]);
            }
            __syncthreads();
#pragma unroll
            for (int ks = 0; ks < 8; ks++) {
#pragma unroll
                for (int j = 0; j < 2; j++) {
                    int row = (ch * 2 + j) * 16 + l16;
                    int c = ks * 4 + q16;
                    h8 bv = *(const h8*)&Ks[row * 256 + ((c ^ (row & 7)) << 3)];
                    sacc[j] = MFMA16(qf[c4 * 8 + ks], bv, sacc[j]);
                }
            }
            __syncthreads();
        }
        // ---- softmax in registers (wave covers 32 key-cols) ----
        float mt[4], st[4];
#pragma unroll
        for (int r = 0; r < 4; r++) mt[r] = fmaxf(sacc[0][r], sacc[1][r]);
#pragma unroll
        for (int m = 1; m <= 8; m <<= 1)
#pragma unroll
            for (int r = 0; r < 4; r++)
                mt[r] = fmaxf(mt[r], __shfl_xor(mt[r], m, 64));
#pragma unroll
        for (int r = 0; r < 4; r++) {
            float s = 0.f;
#pragma unroll
            for (int j = 0; j < 2; j++) {
                float e = __expf(sacc[j][r] - mt[r]);
                sacc[j][r] = e;
                s += e;
            }
            st[r] = s;
        }
#pragma unroll
        for (int m = 1; m <= 8; m <<= 1)
#pragma unroll
            for (int r = 0; r < 4; r++) st[r] += __shfl_xor(st[r], m, 64);
        if (l16 == 0) {
#pragma unroll
            for (int r = 0; r < 4; r++) {
                int row = rb * 16 + q16 * 4 + r;
                Stat[ch][row][0] = mt[r];
                Stat[ch][row][1] = st[r];
            }
        }
        __syncthreads();
        float beta[4];
#pragma unroll
        for (int r = 0; r < 4; r++) {
            int row = rb * 16 + q16 * 4 + r;
            float mmax = Stat[0][row][0];
#pragma unroll
            for (int i = 1; i < 4; i++) mmax = fmaxf(mmax, Stat[i][row][0]);
            float mo = mrun[r];
            float mn = fmaxf(mo, mmax);
            float a = __expf(mo - mn);
            float ssum = 0.f;
#pragma unroll
            for (int i = 0; i < 4; i++)
                ssum += Stat[i][row][1] * __expf(Stat[i][row][0] - mn);
            lrun[r] = lrun[r] * a + ssum;
            mrun[r] = mn;
            beta[r] = __expf(mt[r] - mn);
            if (ch == 0 && l16 == 0) arow[row] = a;
        }
        // P (scaled to new running max) -> LDS, C-layout -> A-layout transpose
#pragma unroll
        for (int j = 0; j < 2; j++)
#pragma unroll
            for (int r = 0; r < 4; r++)
                Ps[(rb * 16 + q16 * 4 + r) * 136 + (ch * 2 + j) * 16 + l16] =
                    (h_t)(sacc[j][r] * beta[r]);
        __syncthreads();
        // ---- rescale O, then O += P @ V'' (wave owns 64 of 512 d-cols) ----
#pragma unroll
        for (int i = 0; i < 2; i++) {
#pragma unroll
            for (int r = 0; r < 4; r++) {
                float a = arow[i * 16 + q16 * 4 + r];
#pragma unroll
                for (int j = 0; j < 4; j++) oacc[i][j][r] *= a;
            }
        }
#pragma unroll
        for (int kstep = 0; kstep < 4; kstep++) {
            h8 pf[2], vf[4];
#pragma unroll
            for (int j = 0; j < 4; j++) {
                int d = w * 64 + j * 16 + l16;
                vf[j] = *(const h8*)(Vbase + (size_t)d * 2048 + kb + kstep * 32 +
                                     q16 * 8);
            }
#pragma unroll
            for (int i = 0; i < 2; i++)
                pf[i] = *(const h8*)&Ps[(i * 16 + l16) * 136 + kstep * 32 + q16 * 8];
#pragma unroll
            for (int i = 0; i < 2; i++)
#pragma unroll
                for (int j = 0; j < 4; j++)
                    oacc[i][j] = MFMA16(pf[i], vf[j], oacc[i][j]);
        }
        // no trailing barrier: next kt's first stage barrier fences Ps/Ks reuse.
    }
    // ---- epilogue: broadcast l, normalize, store fp32 ----
    __syncthreads();
    if (ch == 0 && l16 == 0) {
#pragma unroll
        for (int r = 0; r < 4; r++) arow[rb * 16 + q16 * 4 + r] = lrun[r];
    }
    __syncthreads();
#pragma unroll
    for (int i = 0; i < 2; i++) {
#pragma unroll
        for (int r = 0; r < 4; r++) {
            int row = i * 16 + q16 * 4 + r;
            float inv = 1.f / arow[row];
            size_t orow = ((size_t)b * 2048 + q0 + row) * 512;
#pragma unroll
            for (int j = 0; j < 4; j++) {
                int d = w * 64 + j * 16 + l16;
                Out[orow + d] = oacc[i][j][r] * inv;
            }
        }
    }
}

// ---------------- host ----------------
extern "C" void kernel_launch(void* const* d_in, const int* in_sizes, int n_in,
                              void* d_out, int out_size, void* d_ws, size_t ws_size,
                              hipStream_t stream) {
    const float* S1 = (const float*)d_in[0];
    const float* S2 = (const float*)d_in[1];
    const float* Wq = (const float*)d_in[2];
    const float* Wk = (const float*)d_in[3];
    const float* Wv = (const float*)d_in[4];
    const float* Wo = (const float*)d_in[5];
    const float* bo = (const float*)d_in[6];
    float* Out = (float*)d_out;

    char* ws = (char*)d_ws;
    h_t* S2h  = (h_t*)(ws);                 // 16 MB
    h_t* S1h  = (h_t*)(ws + 16777216);      // 16 MB
    h_t* Wqt  = (h_t*)(ws + 33554432);      // 1 MB
    h_t* Wkt  = (h_t*)(ws + 34603008);      // 1 MB
    h_t* Wvot = (h_t*)(ws + 35651584);      // 0.5 MB
    h_t* Qh   = (h_t*)(ws + 36175872);      // 32 MB
    h_t* Kh   = (h_t*)(ws + 69730304);      // 32 MB
    h_t* Vt   = (h_t*)(ws + 103284736);     // 16 MB -> end 120,061,952
    // Wot/Wvh alias the Qh region: dead before Qh is written.
    h_t* Wot  = (h_t*)(ws + 36175872);      // 1 MB  [512][1024]
    h_t* Wvh  = (h_t*)(ws + 37224448);      // 1 MB  [512][1024]

    k_cast3<<<16896, 256, 0, stream>>>(S1, S2, Wv, S1h, S2h, Wvh);
    k_transpose3<<<dim3(32, 32, 3), 256, 0, stream>>>(Wq, Wk, Wo, Wqt, Wkt, Wot);
    // Wvot[d][c] = sum_e Wot[d][e] * Wvh[c][e] = (Wv @ Wo)^T
    k_gemm<<<dim3(4, 4), 256, 0, stream>>>(Wot, Wvh, Wvot, 512, 512, 1024);
    k_gemm<<<dim3(128, 8), 256, 0, stream>>>(S2h, Wqt, Qh, 16384, 1024, 512);
    k_gemm<<<dim3(128, 8), 256, 0, stream>>>(S1h, Wkt, Kh, 16384, 1024, 512);
    k_gemm_vt<<<dim3(128, 4), 256, 0, stream>>>(S1h, Wvot, bo, Vt, 16384, 512, 512);
    k_attn<<<512, 512, 0, stream>>>(Qh, Kh, Vt, Out);
}

// Round 5
// 553.751 us; speedup vs baseline: 1.1515x; 1.1515x over previous
//
#include <hip/hip_runtime.h>

// CrossAttention: out = softmax((S2 Wq)(S1 Wk)^T) (S1 Wv) Wo + bo
// Refactored: Wvo = Wv@Wo (512x512);  V'' = S1@Wvo + bo;  out = softmax(QK^T) @ V''
// fp16 MFMA (16x16x32), fp32 accumulate.
// R5: attention rebuilt as 256-thread/4-wave blocks, Q-tile 32, K-tile 128.
// Q fragments re-read from L2 each chunk (no 128-VGPR resident Q) -> total
// regs ~180 -> TWO independent blocks/CU, so one block's MFMA hides the other
// block's stage/barrier drains. Staging keeps the proven stage->barrier->
// compute->barrier pattern (no async pipelining).

typedef _Float16 h_t;
typedef _Float16 h8 __attribute__((ext_vector_type(8)));
typedef _Float16 h4 __attribute__((ext_vector_type(4)));
typedef float f4 __attribute__((ext_vector_type(4)));

#define MFMA16(a, b, c) __builtin_amdgcn_mfma_f32_16x16x32_f16(a, b, c, 0, 0, 0)

typedef const __attribute__((address_space(1))) void* gas_t;
typedef __attribute__((address_space(3))) void* las_t;

__device__ __forceinline__ void gl2lds16(const void* g, void* l) {
    __builtin_amdgcn_global_load_lds((gas_t)g, (las_t)l, 16, 0, 0);
}

// ---------------- merged cast fp32 -> fp16: S1, S2, Wv ----------------
__global__ __launch_bounds__(256) void k_cast3(const float* __restrict__ S1,
                                               const float* __restrict__ S2,
                                               const float* __restrict__ Wv,
                                               h_t* __restrict__ S1h,
                                               h_t* __restrict__ S2h,
                                               h_t* __restrict__ Wvh) {
    long i = (long)blockIdx.x * 256 + threadIdx.x;  // f4 index
    const long n = 2097152;                          // S1/S2 f4 count
    const float* src;
    h_t* dst;
    long off;
    if (i < n) { src = S1; dst = S1h; off = i; }
    else if (i < 2 * n) { src = S2; dst = S2h; off = i - n; }
    else { src = Wv; dst = Wvh; off = i - 2 * n; }
    float4 v = *((const float4*)src + off);
    h4 h = {(h_t)v.x, (h_t)v.y, (h_t)v.z, (h_t)v.w};
    *((h4*)dst + off) = h;
}

// ---------------- merged transpose+cast: Wq, Wk, Wo -> [N][K] f16 ----------------
__global__ __launch_bounds__(256) void k_transpose3(const float* __restrict__ Wq,
                                                    const float* __restrict__ Wk,
                                                    const float* __restrict__ Wo,
                                                    h_t* __restrict__ Wqt,
                                                    h_t* __restrict__ Wkt,
                                                    h_t* __restrict__ Wot) {
    const float* in;
    h_t* out;
    int K, N;
    if (blockIdx.z == 0) { in = Wq; out = Wqt; K = 512; N = 1024; }
    else if (blockIdx.z == 1) { in = Wk; out = Wkt; K = 512; N = 1024; }
    else { in = Wo; out = Wot; K = 1024; N = 512; }
    int kb = blockIdx.y * 32, nb = blockIdx.x * 32;
    if (kb >= K || nb >= N) return;
    __shared__ float tile[32][33];
    int x = threadIdx.x & 31, y = threadIdx.x >> 5;
#pragma unroll
    for (int j = 0; j < 4; j++)
        tile[y + j * 8][x] = in[(size_t)(kb + y + j * 8) * N + nb + x];
    __syncthreads();
#pragma unroll
    for (int j = 0; j < 4; j++)
        out[(size_t)(nb + y + j * 8) * K + kb + x] = (h_t)tile[x][y + j * 8];
}

// ---------------- m97-style NT GEMM: C[M][N] f16 = A[M][K] x Bt[N][K]^T ------------
__global__ __launch_bounds__(256) void k_gemm(const h_t* __restrict__ A,
                                              const h_t* __restrict__ Bt,
                                              h_t* __restrict__ C,
                                              int M, int N, int K) {
    __shared__ h_t As[128 * 64];
    __shared__ h_t Bs[128 * 64];
    int t = threadIdx.x, w = t >> 6, lane = t & 63;
    int q16 = lane >> 4, l16 = lane & 15;
    size_t m0 = (size_t)blockIdx.x * 128, n0 = (size_t)blockIdx.y * 128;
    int wr = (w >> 1) * 64, wc = (w & 1) * 64;
    f4 acc[4][4] = {};

    for (int k0 = 0; k0 < K; k0 += 64) {
#pragma unroll
        for (int j = 0; j < 4; j++) {
            int q = w * 4 + j;
            int row = q * 8 + (lane >> 3);
            int ks = (((lane & 7) ^ (row & 7)) << 3);
            gl2lds16(A + (m0 + row) * K + k0 + ks, &As[q * 512]);
            gl2lds16(Bt + (n0 + row) * K + k0 + ks, &Bs[q * 512]);
        }
        __syncthreads();
#pragma unroll
        for (int ks = 0; ks < 2; ks++) {
            h8 av[4], bv[4];
#pragma unroll
            for (int i = 0; i < 4; i++) {
                int row = wr + i * 16 + l16;
                int ch = ks * 4 + q16;
                av[i] = *(const h8*)&As[row * 64 + ((ch ^ (row & 7)) << 3)];
            }
#pragma unroll
            for (int j = 0; j < 4; j++) {
                int row = wc + j * 16 + l16;
                int ch = ks * 4 + q16;
                bv[j] = *(const h8*)&Bs[row * 64 + ((ch ^ (row & 7)) << 3)];
            }
#pragma unroll
            for (int i = 0; i < 4; i++)
#pragma unroll
                for (int j = 0; j < 4; j++)
                    acc[i][j] = MFMA16(av[i], bv[j], acc[i][j]);
        }
        __syncthreads();
    }
#pragma unroll
    for (int i = 0; i < 4; i++) {
        size_t r0 = m0 + wr + i * 16 + q16 * 4;
#pragma unroll
        for (int j = 0; j < 4; j++) {
            size_t c = n0 + wc + j * 16 + l16;
#pragma unroll
            for (int r = 0; r < 4; r++)
                C[(r0 + r) * N + c] = (h_t)acc[i][j][r];
        }
    }
}

// ---------------- V'' GEMM: +bias, transposed store Vt[b][d][n] -------------------
__global__ __launch_bounds__(256) void k_gemm_vt(const h_t* __restrict__ A,
                                                 const h_t* __restrict__ Bt,
                                                 const float* __restrict__ bo,
                                                 h_t* __restrict__ Vt,
                                                 int M, int N, int K) {
    __shared__ h_t As[128 * 64];
    __shared__ h_t Bs[128 * 64];
    int t = threadIdx.x, w = t >> 6, lane = t & 63;
    int q16 = lane >> 4, l16 = lane & 15;
    size_t m0 = (size_t)blockIdx.x * 128, n0 = (size_t)blockIdx.y * 128;
    int wr = (w >> 1) * 64, wc = (w & 1) * 64;
    f4 acc[4][4] = {};

    for (int k0 = 0; k0 < K; k0 += 64) {
#pragma unroll
        for (int j = 0; j < 4; j++) {
            int q = w * 4 + j;
            int row = q * 8 + (lane >> 3);
            int ks = (((lane & 7) ^ (row & 7)) << 3);
            gl2lds16(A + (m0 + row) * K + k0 + ks, &As[q * 512]);
            gl2lds16(Bt + (n0 + row) * K + k0 + ks, &Bs[q * 512]);
        }
        __syncthreads();
#pragma unroll
        for (int ks = 0; ks < 2; ks++) {
            h8 av[4], bv[4];
#pragma unroll
            for (int i = 0; i < 4; i++) {
                int row = wr + i * 16 + l16;
                int ch = ks * 4 + q16;
                av[i] = *(const h8*)&As[row * 64 + ((ch ^ (row & 7)) << 3)];
            }
#pragma unroll
            for (int j = 0; j < 4; j++) {
                int row = wc + j * 16 + l16;
                int ch = ks * 4 + q16;
                bv[j] = *(const h8*)&Bs[row * 64 + ((ch ^ (row & 7)) << 3)];
            }
#pragma unroll
            for (int i = 0; i < 4; i++)
#pragma unroll
                for (int j = 0; j < 4; j++)
                    acc[i][j] = MFMA16(av[i], bv[j], acc[i][j]);
        }
        __syncthreads();
    }
#pragma unroll
    for (int i = 0; i < 4; i++) {
        size_t gm = m0 + wr + i * 16 + q16 * 4;
        size_t b = gm >> 11;
        size_t n = gm & 2047;
#pragma unroll
        for (int j = 0; j < 4; j++) {
            size_t d = n0 + wc + j * 16 + l16;
            float bias = bo[d];
            h4 hv = {(h_t)(acc[i][j][0] + bias), (h_t)(acc[i][j][1] + bias),
                     (h_t)(acc[i][j][2] + bias), (h_t)(acc[i][j][3] + bias)};
            *(h4*)&Vt[(b * 512 + d) * 2048 + n] = hv;
        }
    }
}

// ---------------- fused flash attention (4-wave blocks, 2 blocks/CU) --------------
// 512 blocks x 256 threads (4 waves = 2 row-bands x 2 key-halves). Q-tile 32,
// K-tile 128 staged as 8 chunks of 128-inner (32 KB LDS, stage->barrier->
// compute->barrier). Q fragments re-read from L2 per chunk (no resident Q).
// Per-wave register softmax + 2-way Stat combine. LDS ~42 KB, regs ~180 ->
// 2 independent blocks/CU: TLP hides the barrier/vmcnt drains.
__global__ __launch_bounds__(256, 2) void k_attn(const h_t* __restrict__ Qh,
                                                 const h_t* __restrict__ Kh,
                                                 const h_t* __restrict__ Vt,
                                                 float* __restrict__ Out) {
    __shared__ h_t Ks[128 * 128];     // 32 KB, XOR-swizzled 16B granules
    __shared__ h_t Ps[32 * 136];      // 8.7 KB probs, padded stride
    __shared__ float Stat[2][32][2];  // per key-half (max, sumexp)
    __shared__ float arow[32];        // broadcast alpha / final l

    int t = threadIdx.x, w = t >> 6, lane = t & 63;
    int q16 = lane >> 4, l16 = lane & 15;
    int rb = w & 1, ch = w >> 1;      // row band (0..1), key half (0..1)
    int b = blockIdx.x & 7;
    int q0 = (blockIdx.x >> 3) * 32;

    const h_t* Kbase = Kh + (size_t)b * 2048 * 1024;
    const h_t* Vbase = Vt + (size_t)b * 512 * 2048;
    // A-fragment source for this lane: row rb*16+l16, k = q16*8 (+32 per kstep)
    const h_t* Qrow = Qh + ((size_t)b * 2048 + q0 + rb * 16 + l16) * 1024 + q16 * 8;

    f4 oacc[2][8] = {};
    float mrun[4] = {-1e30f, -1e30f, -1e30f, -1e30f};
    float lrun[4] = {0.f, 0.f, 0.f, 0.f};

    for (int kt = 0; kt < 16; kt++) {
        int kb = kt * 128;
        f4 sacc[4] = {};
        // ---- S = Q K^T over inner 1024, staged in 8 chunks of 128 ----
#pragma unroll 1
        for (int c8 = 0; c8 < 8; c8++) {
#pragma unroll
            for (int j = 0; j < 8; j++) {
                int rowc = w * 32 + j * 4 + (lane >> 4);   // 0..127 chunk row
                int kg = (lane & 15) ^ (rowc & 7);         // swizzled src granule
                gl2lds16(Kbase + (size_t)(kb + rowc) * 1024 + c8 * 128 + kg * 8,
                         &Ks[(w * 32 + j * 4) * 128]);
            }
            __syncthreads();
            h8 qv[4];
#pragma unroll
            for (int ks = 0; ks < 4; ks++)
                qv[ks] = *(const h8*)(Qrow + c8 * 128 + ks * 32);
#pragma unroll
            for (int ks = 0; ks < 4; ks++) {
#pragma unroll
                for (int j = 0; j < 4; j++) {
                    int kr = ch * 64 + j * 16 + l16;
                    int g = ks * 4 + q16;
                    h8 bv = *(const h8*)&Ks[kr * 128 + ((g ^ (kr & 7)) << 3)];
                    sacc[j] = MFMA16(qv[ks], bv, sacc[j]);
                }
            }
            __syncthreads();
        }
        // ---- softmax in registers (wave covers 64 key-cols) ----
        float mt[4], st[4];
#pragma unroll
        for (int r = 0; r < 4; r++)
            mt[r] = fmaxf(fmaxf(sacc[0][r], sacc[1][r]),
                          fmaxf(sacc[2][r], sacc[3][r]));
#pragma unroll
        for (int m = 1; m <= 8; m <<= 1)
#pragma unroll
            for (int r = 0; r < 4; r++)
                mt[r] = fmaxf(mt[r], __shfl_xor(mt[r], m, 64));
#pragma unroll
        for (int r = 0; r < 4; r++) {
            float s = 0.f;
#pragma unroll
            for (int j = 0; j < 4; j++) {
                float e = __expf(sacc[j][r] - mt[r]);
                sacc[j][r] = e;
                s += e;
            }
            st[r] = s;
        }
#pragma unroll
        for (int m = 1; m <= 8; m <<= 1)
#pragma unroll
            for (int r = 0; r < 4; r++) st[r] += __shfl_xor(st[r], m, 64);
        if (l16 == 0) {
#pragma unroll
            for (int r = 0; r < 4; r++) {
                int row = rb * 16 + q16 * 4 + r;
                Stat[ch][row][0] = mt[r];
                Stat[ch][row][1] = st[r];
            }
        }
        __syncthreads();
        float beta[4];
#pragma unroll
        for (int r = 0; r < 4; r++) {
            int row = rb * 16 + q16 * 4 + r;
            float m0 = Stat[0][row][0], s0 = Stat[0][row][1];
            float m1 = Stat[1][row][0], s1 = Stat[1][row][1];
            float mo = mrun[r];
            float mn = fmaxf(mo, fmaxf(m0, m1));
            float a = __expf(mo - mn);
            lrun[r] = lrun[r] * a + s0 * __expf(m0 - mn) + s1 * __expf(m1 - mn);
            mrun[r] = mn;
            beta[r] = __expf(mt[r] - mn);
            if (ch == 0 && l16 == 0) arow[row] = a;
        }
        // P (scaled to new running max) -> LDS, C-layout -> A-layout transpose
#pragma unroll
        for (int j = 0; j < 4; j++)
#pragma unroll
            for (int r = 0; r < 4; r++)
                Ps[(rb * 16 + q16 * 4 + r) * 136 + ch * 64 + j * 16 + l16] =
                    (h_t)(sacc[j][r] * beta[r]);
        __syncthreads();
        // ---- rescale O, then O += P @ V'' (wave owns 128 of 512 d-cols) ----
#pragma unroll
        for (int i = 0; i < 2; i++) {
#pragma unroll
            for (int r = 0; r < 4; r++) {
                float a = arow[i * 16 + q16 * 4 + r];
#pragma unroll
                for (int j = 0; j < 8; j++) oacc[i][j][r] *= a;
            }
        }
#pragma unroll
        for (int kstep = 0; kstep < 4; kstep++) {
            h8 pf[2];
#pragma unroll
            for (int i = 0; i < 2; i++)
                pf[i] = *(const h8*)&Ps[(i * 16 + l16) * 136 + kstep * 32 + q16 * 8];
#pragma unroll
            for (int jh = 0; jh < 2; jh++) {
                h8 vf[4];
#pragma unroll
                for (int j4 = 0; j4 < 4; j4++) {
                    int d = w * 128 + (jh * 4 + j4) * 16 + l16;
                    vf[j4] = *(const h8*)(Vbase + (size_t)d * 2048 + kb +
                                          kstep * 32 + q16 * 8);
                }
#pragma unroll
                for (int i = 0; i < 2; i++)
#pragma unroll
                    for (int j4 = 0; j4 < 4; j4++)
                        oacc[i][jh * 4 + j4] =
                            MFMA16(pf[i], vf[j4], oacc[i][jh * 4 + j4]);
            }
        }
        // next kt's first staging barrier fences Ps/arow reuse.
    }
    // ---- epilogue: broadcast l, normalize, store fp32 ----
    __syncthreads();
    if (ch == 0 && l16 == 0) {
#pragma unroll
        for (int r = 0; r < 4; r++) arow[rb * 16 + q16 * 4 + r] = lrun[r];
    }
    __syncthreads();
#pragma unroll
    for (int i = 0; i < 2; i++) {
#pragma unroll
        for (int r = 0; r < 4; r++) {
            int row = i * 16 + q16 * 4 + r;
            float inv = 1.f / arow[row];
            size_t orow = ((size_t)b * 2048 + q0 + row) * 512;
#pragma unroll
            for (int j = 0; j < 8; j++) {
                int d = w * 128 + j * 16 + l16;
                Out[orow + d] = oacc[i][j][r] * inv;
            }
        }
    }
}

// ---------------- host ----------------
extern "C" void kernel_launch(void* const* d_in, const int* in_sizes, int n_in,
                              void* d_out, int out_size, void* d_ws, size_t ws_size,
                              hipStream_t stream) {
    const float* S1 = (const float*)d_in[0];
    const float* S2 = (const float*)d_in[1];
    const float* Wq = (const float*)d_in[2];
    const float* Wk = (const float*)d_in[3];
    const float* Wv = (const float*)d_in[4];
    const float* Wo = (const float*)d_in[5];
    const float* bo = (const float*)d_in[6];
    float* Out = (float*)d_out;

    char* ws = (char*)d_ws;
    h_t* S2h  = (h_t*)(ws);                 // 16 MB
    h_t* S1h  = (h_t*)(ws + 16777216);      // 16 MB
    h_t* Wqt  = (h_t*)(ws + 33554432);      // 1 MB
    h_t* Wkt  = (h_t*)(ws + 34603008);      // 1 MB
    h_t* Wvot = (h_t*)(ws + 35651584);      // 0.5 MB
    h_t* Qh   = (h_t*)(ws + 36175872);      // 32 MB
    h_t* Kh   = (h_t*)(ws + 69730304);      // 32 MB
    h_t* Vt   = (h_t*)(ws + 103284736);     // 16 MB -> end 120,061,952
    // Wot/Wvh alias the Qh region: dead before Qh is written.
    h_t* Wot  = (h_t*)(ws + 36175872);      // 1 MB  [512][1024]
    h_t* Wvh  = (h_t*)(ws + 37224448);      // 1 MB  [512][1024]

    k_cast3<<<16896, 256, 0, stream>>>(S1, S2, Wv, S1h, S2h, Wvh);
    k_transpose3<<<dim3(32, 32, 3), 256, 0, stream>>>(Wq, Wk, Wo, Wqt, Wkt, Wot);
    // Wvot[d][c] = sum_e Wot[d][e] * Wvh[c][e] = (Wv @ Wo)^T
    k_gemm<<<dim3(4, 4), 256, 0, stream>>>(Wot, Wvh, Wvot, 512, 512, 1024);
    k_gemm<<<dim3(128, 8), 256, 0, stream>>>(S2h, Wqt, Qh, 16384, 1024, 512);
    k_gemm<<<dim3(128, 8), 256, 0, stream>>>(S1h, Wkt, Kh, 16384, 1024, 512);
    k_gemm_vt<<<dim3(128, 4), 256, 0, stream>>>(S1h, Wvot, bo, Vt, 16384, 512, 512);
    k_attn<<<512, 256, 0, stream>>>(Qh, Kh, Vt, Out);
}

// Round 6
// 414.308 us; speedup vs baseline: 1.5390x; 1.3366x over previous
//
#include <hip/hip_runtime.h>

// CrossAttention: out = softmax((S2 Wq)(S1 Wk)^T) (S1 Wv) Wo + bo
// Refactored: Wvo = Wv@Wo;  V'' = S1@Wvo + bo;  out = softmax(QK^T) @ V''
// R6: attention = Q-tile 128 x key-half split (Flash-Decoding). Each of 256
// blocks (1/CU) does 128 Q-rows x 1024 keys with m97-style both-sided LDS
// staging (BK=128), wave-local softmax (8 waves = 8 row-bands, no cross-wave
// combine), PV from global V. Partial O (normalized, fp16) + (m,l) stored to
// dead workspace; k_comb merges the two key-halves. Strict stage->sync->
// compute->sync staging (no cross-iteration pipelining).

typedef _Float16 h_t;
typedef _Float16 h8 __attribute__((ext_vector_type(8)));
typedef _Float16 h4 __attribute__((ext_vector_type(4)));
typedef float f4 __attribute__((ext_vector_type(4)));

#define MFMA16(a, b, c) __builtin_amdgcn_mfma_f32_16x16x32_f16(a, b, c, 0, 0, 0)

typedef const __attribute__((address_space(1))) void* gas_t;
typedef __attribute__((address_space(3))) void* las_t;

__device__ __forceinline__ void gl2lds16(const void* g, void* l) {
    __builtin_amdgcn_global_load_lds((gas_t)g, (las_t)l, 16, 0, 0);
}

// ---------------- merged cast fp32 -> fp16: S1, S2, Wv ----------------
__global__ __launch_bounds__(256) void k_cast3(const float* __restrict__ S1,
                                               const float* __restrict__ S2,
                                               const float* __restrict__ Wv,
                                               h_t* __restrict__ S1h,
                                               h_t* __restrict__ S2h,
                                               h_t* __restrict__ Wvh) {
    long i = (long)blockIdx.x * 256 + threadIdx.x;  // f4 index
    const long n = 2097152;                          // S1/S2 f4 count
    const float* src;
    h_t* dst;
    long off;
    if (i < n) { src = S1; dst = S1h; off = i; }
    else if (i < 2 * n) { src = S2; dst = S2h; off = i - n; }
    else { src = Wv; dst = Wvh; off = i - 2 * n; }
    float4 v = *((const float4*)src + off);
    h4 h = {(h_t)v.x, (h_t)v.y, (h_t)v.z, (h_t)v.w};
    *((h4*)dst + off) = h;
}

// ---------------- merged transpose+cast: Wq, Wk, Wo -> [N][K] f16 ----------------
__global__ __launch_bounds__(256) void k_transpose3(const float* __restrict__ Wq,
                                                    const float* __restrict__ Wk,
                                                    const float* __restrict__ Wo,
                                                    h_t* __restrict__ Wqt,
                                                    h_t* __restrict__ Wkt,
                                                    h_t* __restrict__ Wot) {
    const float* in;
    h_t* out;
    int K, N;
    if (blockIdx.z == 0) { in = Wq; out = Wqt; K = 512; N = 1024; }
    else if (blockIdx.z == 1) { in = Wk; out = Wkt; K = 512; N = 1024; }
    else { in = Wo; out = Wot; K = 1024; N = 512; }
    int kb = blockIdx.y * 32, nb = blockIdx.x * 32;
    if (kb >= K || nb >= N) return;
    __shared__ float tile[32][33];
    int x = threadIdx.x & 31, y = threadIdx.x >> 5;
#pragma unroll
    for (int j = 0; j < 4; j++)
        tile[y + j * 8][x] = in[(size_t)(kb + y + j * 8) * N + nb + x];
    __syncthreads();
#pragma unroll
    for (int j = 0; j < 4; j++)
        out[(size_t)(nb + y + j * 8) * K + kb + x] = (h_t)tile[x][y + j * 8];
}

// ---------------- m97-style NT GEMM: C[M][N] f16 = A[M][K] x Bt[N][K]^T ------------
__global__ __launch_bounds__(256) void k_gemm(const h_t* __restrict__ A,
                                              const h_t* __restrict__ Bt,
                                              h_t* __restrict__ C,
                                              int M, int N, int K) {
    __shared__ h_t As[128 * 64];
    __shared__ h_t Bs[128 * 64];
    int t = threadIdx.x, w = t >> 6, lane = t & 63;
    int q16 = lane >> 4, l16 = lane & 15;
    size_t m0 = (size_t)blockIdx.x * 128, n0 = (size_t)blockIdx.y * 128;
    int wr = (w >> 1) * 64, wc = (w & 1) * 64;
    f4 acc[4][4] = {};

    for (int k0 = 0; k0 < K; k0 += 64) {
#pragma unroll
        for (int j = 0; j < 4; j++) {
            int q = w * 4 + j;
            int row = q * 8 + (lane >> 3);
            int ks = (((lane & 7) ^ (row & 7)) << 3);
            gl2lds16(A + (m0 + row) * K + k0 + ks, &As[q * 512]);
            gl2lds16(Bt + (n0 + row) * K + k0 + ks, &Bs[q * 512]);
        }
        __syncthreads();
#pragma unroll
        for (int ks = 0; ks < 2; ks++) {
            h8 av[4], bv[4];
#pragma unroll
            for (int i = 0; i < 4; i++) {
                int row = wr + i * 16 + l16;
                int ch = ks * 4 + q16;
                av[i] = *(const h8*)&As[row * 64 + ((ch ^ (row & 7)) << 3)];
            }
#pragma unroll
            for (int j = 0; j < 4; j++) {
                int row = wc + j * 16 + l16;
                int ch = ks * 4 + q16;
                bv[j] = *(const h8*)&Bs[row * 64 + ((ch ^ (row & 7)) << 3)];
            }
#pragma unroll
            for (int i = 0; i < 4; i++)
#pragma unroll
                for (int j = 0; j < 4; j++)
                    acc[i][j] = MFMA16(av[i], bv[j], acc[i][j]);
        }
        __syncthreads();
    }
#pragma unroll
    for (int i = 0; i < 4; i++) {
        size_t r0 = m0 + wr + i * 16 + q16 * 4;
#pragma unroll
        for (int j = 0; j < 4; j++) {
            size_t c = n0 + wc + j * 16 + l16;
#pragma unroll
            for (int r = 0; r < 4; r++)
                C[(r0 + r) * N + c] = (h_t)acc[i][j][r];
        }
    }
}

// ---------------- V'' GEMM: +bias, transposed store Vt[b][d][n] -------------------
__global__ __launch_bounds__(256) void k_gemm_vt(const h_t* __restrict__ A,
                                                 const h_t* __restrict__ Bt,
                                                 const float* __restrict__ bo,
                                                 h_t* __restrict__ Vt,
                                                 int M, int N, int K) {
    __shared__ h_t As[128 * 64];
    __shared__ h_t Bs[128 * 64];
    int t = threadIdx.x, w = t >> 6, lane = t & 63;
    int q16 = lane >> 4, l16 = lane & 15;
    size_t m0 = (size_t)blockIdx.x * 128, n0 = (size_t)blockIdx.y * 128;
    int wr = (w >> 1) * 64, wc = (w & 1) * 64;
    f4 acc[4][4] = {};

    for (int k0 = 0; k0 < K; k0 += 64) {
#pragma unroll
        for (int j = 0; j < 4; j++) {
            int q = w * 4 + j;
            int row = q * 8 + (lane >> 3);
            int ks = (((lane & 7) ^ (row & 7)) << 3);
            gl2lds16(A + (m0 + row) * K + k0 + ks, &As[q * 512]);
            gl2lds16(Bt + (n0 + row) * K + k0 + ks, &Bs[q * 512]);
        }
        __syncthreads();
#pragma unroll
        for (int ks = 0; ks < 2; ks++) {
            h8 av[4], bv[4];
#pragma unroll
            for (int i = 0; i < 4; i++) {
                int row = wr + i * 16 + l16;
                int ch = ks * 4 + q16;
                av[i] = *(const h8*)&As[row * 64 + ((ch ^ (row & 7)) << 3)];
            }
#pragma unroll
            for (int j = 0; j < 4; j++) {
                int row = wc + j * 16 + l16;
                int ch = ks * 4 + q16;
                bv[j] = *(const h8*)&Bs[row * 64 + ((ch ^ (row & 7)) << 3)];
            }
#pragma unroll
            for (int i = 0; i < 4; i++)
#pragma unroll
                for (int j = 0; j < 4; j++)
                    acc[i][j] = MFMA16(av[i], bv[j], acc[i][j]);
        }
        __syncthreads();
    }
#pragma unroll
    for (int i = 0; i < 4; i++) {
        size_t gm = m0 + wr + i * 16 + q16 * 4;
        size_t b = gm >> 11;
        size_t n = gm & 2047;
#pragma unroll
        for (int j = 0; j < 4; j++) {
            size_t d = n0 + wc + j * 16 + l16;
            float bias = bo[d];
            h4 hv = {(h_t)(acc[i][j][0] + bias), (h_t)(acc[i][j][1] + bias),
                     (h_t)(acc[i][j][2] + bias), (h_t)(acc[i][j][3] + bias)};
            *(h4*)&Vt[(b * 512 + d) * 2048 + n] = hv;
        }
    }
}

// ---------------- flash attention, Q-tile 128, key-half split ----------------
// 256 blocks x 512 threads (8 waves = 8 row-bands of 16 Q-rows). Each block:
// 128 Q-rows x 1024 keys (half), inner 1024 in BK=128 chunks with BOTH Q and K
// staged via gl2lds (strict stage->sync->compute->sync). Softmax wave-local.
// Emits normalized partial O (fp16) + (m,l) per row for k_comb.
__global__ __launch_bounds__(512, 2) void k_attn(const h_t* __restrict__ Qh,
                                                 const h_t* __restrict__ Kh,
                                                 const h_t* __restrict__ Vt,
                                                 h_t* __restrict__ Obar,
                                                 float2* __restrict__ Ml) {
    __shared__ h_t Qs[128 * 128];   // 32 KB
    __shared__ h_t Ks[128 * 128];   // 32 KB
    __shared__ h_t Ps[128 * 136];   // 34.8 KB
    __shared__ float arow[128];

    int t = threadIdx.x, w = t >> 6, lane = t & 63;
    int q16 = lane >> 4, l16 = lane & 15;
    int b = blockIdx.x & 7;
    int half = (blockIdx.x >> 3) & 1;
    int qt = blockIdx.x >> 4;
    int q0 = qt * 128;
    int kh0 = half * 1024;
    int rof = lane >> 4, g = lane & 15;

    const h_t* Qbase = Qh + ((size_t)b * 2048 + q0) * 1024;
    const h_t* Kbase = Kh + (size_t)b * 2048 * 1024;
    const h_t* Vbase = Vt + (size_t)b * 512 * 2048;

    f4 oacc[8][4] = {};
    float mrun[4] = {-1e30f, -1e30f, -1e30f, -1e30f};
    float lrun[4] = {0.f, 0.f, 0.f, 0.f};

    for (int kt = 0; kt < 8; kt++) {
        int kb = kh0 + kt * 128;
        f4 sacc[8] = {};
        // ---- S = Q K^T over inner 1024 in 8 chunks of 128 (both staged) ----
#pragma unroll 1
        for (int c = 0; c < 8; c++) {
#pragma unroll
            for (int j = 0; j < 4; j++) {
                int row = w * 16 + j * 4 + rof;
                int gsrc = g ^ (row & 7);
                gl2lds16(Qbase + (size_t)row * 1024 + c * 128 + gsrc * 8,
                         &Qs[(w * 16 + j * 4) * 128]);
            }
#pragma unroll
            for (int j = 0; j < 4; j++) {
                int row = w * 16 + j * 4 + rof;
                int gsrc = g ^ (row & 7);
                gl2lds16(Kbase + (size_t)(kb + row) * 1024 + c * 128 + gsrc * 8,
                         &Ks[(w * 16 + j * 4) * 128]);
            }
            __syncthreads();
            int ar = w * 16 + l16;
#pragma unroll
            for (int ks = 0; ks < 4; ks++) {
                h8 qa = *(const h8*)&Qs[ar * 128 + (((ks * 4 + q16) ^ (ar & 7)) << 3)];
#pragma unroll
                for (int j = 0; j < 8; j++) {
                    int kr = j * 16 + l16;
                    h8 bv = *(const h8*)&Ks[kr * 128 + (((ks * 4 + q16) ^ (kr & 7)) << 3)];
                    sacc[j] = MFMA16(qa, bv, sacc[j]);
                }
            }
            __syncthreads();
        }
        // ---- wave-local softmax over this kt's 128 keys ----
        float mt[4], st[4], beta[4];
#pragma unroll
        for (int r = 0; r < 4; r++) {
            float m = sacc[0][r];
#pragma unroll
            for (int j = 1; j < 8; j++) m = fmaxf(m, sacc[j][r]);
            mt[r] = m;
        }
#pragma unroll
        for (int m = 1; m <= 8; m <<= 1)
#pragma unroll
            for (int r = 0; r < 4; r++)
                mt[r] = fmaxf(mt[r], __shfl_xor(mt[r], m, 64));
#pragma unroll
        for (int r = 0; r < 4; r++) {
            float s = 0.f;
#pragma unroll
            for (int j = 0; j < 8; j++) {
                float e = __expf(sacc[j][r] - mt[r]);
                sacc[j][r] = e;
                s += e;
            }
            st[r] = s;
        }
#pragma unroll
        for (int m = 1; m <= 8; m <<= 1)
#pragma unroll
            for (int r = 0; r < 4; r++) st[r] += __shfl_xor(st[r], m, 64);
#pragma unroll
        for (int r = 0; r < 4; r++) {
            float mo = mrun[r];
            float mn = fmaxf(mo, mt[r]);
            float a = __expf(mo - mn);
            float bb = __expf(mt[r] - mn);
            lrun[r] = lrun[r] * a + st[r] * bb;
            mrun[r] = mn;
            beta[r] = bb;
            if (l16 == 0) arow[w * 16 + q16 * 4 + r] = a;
        }
        // P (rescaled) -> LDS, C-layout -> A-layout
#pragma unroll
        for (int j = 0; j < 8; j++)
#pragma unroll
            for (int r = 0; r < 4; r++)
                Ps[(w * 16 + q16 * 4 + r) * 136 + j * 16 + l16] =
                    (h_t)(sacc[j][r] * beta[r]);
        __syncthreads();
        // ---- rescale O, then O += P @ V'' (wave owns 64 of 512 d-cols) ----
#pragma unroll
        for (int i = 0; i < 8; i++) {
#pragma unroll
            for (int r = 0; r < 4; r++) {
                float a = arow[i * 16 + q16 * 4 + r];
#pragma unroll
                for (int j = 0; j < 4; j++) oacc[i][j][r] *= a;
            }
        }
#pragma unroll
        for (int ks = 0; ks < 4; ks++) {
            h8 vf[4];
#pragma unroll
            for (int j = 0; j < 4; j++) {
                int d = w * 64 + j * 16 + l16;
                vf[j] = *(const h8*)(Vbase + (size_t)d * 2048 + kb + ks * 32 + q16 * 8);
            }
#pragma unroll
            for (int i = 0; i < 8; i++) {
                h8 pf = *(const h8*)&Ps[(i * 16 + l16) * 136 + ks * 32 + q16 * 8];
#pragma unroll
                for (int j = 0; j < 4; j++)
                    oacc[i][j] = MFMA16(pf, vf[j], oacc[i][j]);
            }
        }
        __syncthreads();  // Ps/arow consumed before next kt rewrites them
    }
    // ---- epilogue: partial O (normalized by this half's l), m/l out ----
    if (l16 == 0) {
#pragma unroll
        for (int r = 0; r < 4; r++) arow[w * 16 + q16 * 4 + r] = lrun[r];
    }
    __syncthreads();
    size_t obase = (size_t)(half * 8 + b) * 2048 + q0;
#pragma unroll
    for (int i = 0; i < 8; i++) {
#pragma unroll
        for (int r = 0; r < 4; r++) {
            int row = i * 16 + q16 * 4 + r;
            float inv = 1.f / arow[row];
#pragma unroll
            for (int j = 0; j < 4; j++) {
                int d = w * 64 + j * 16 + l16;
                Obar[(obase + row) * 512 + d] = (h_t)(oacc[i][j][r] * inv);
            }
        }
    }
    if (l16 == 0) {
#pragma unroll
        for (int r = 0; r < 4; r++) {
            int row = w * 16 + q16 * 4 + r;
            Ml[obase + row] = make_float2(mrun[r], lrun[r]);
        }
    }
}

// ---------------- combine the two key-halves ----------------
__global__ __launch_bounds__(256) void k_comb(const h_t* __restrict__ Obar,
                                              const float2* __restrict__ Ml,
                                              float* __restrict__ Out) {
    int gid = blockIdx.x * 256 + threadIdx.x;  // 2,097,152 = 16384 rows x 128 d4
    int d4 = gid & 127;
    int rg = gid >> 7;  // b*2048 + row
    float2 ml0 = Ml[rg], ml1 = Ml[16384 + rg];
    float m = fmaxf(ml0.x, ml1.x);
    float w0 = ml0.y * __expf(ml0.x - m);
    float w1 = ml1.y * __expf(ml1.x - m);
    float inv = 1.f / (w0 + w1);
    w0 *= inv;
    w1 *= inv;
    h4 o0 = *(const h4*)&Obar[(size_t)rg * 512 + d4 * 4];
    h4 o1 = *(const h4*)&Obar[((size_t)16384 + rg) * 512 + d4 * 4];
    float4 o;
    o.x = w0 * (float)o0[0] + w1 * (float)o1[0];
    o.y = w0 * (float)o0[1] + w1 * (float)o1[1];
    o.z = w0 * (float)o0[2] + w1 * (float)o1[2];
    o.w = w0 * (float)o0[3] + w1 * (float)o1[3];
    *(float4*)&Out[(size_t)rg * 512 + d4 * 4] = o;
}

// ---------------- host ----------------
extern "C" void kernel_launch(void* const* d_in, const int* in_sizes, int n_in,
                              void* d_out, int out_size, void* d_ws, size_t ws_size,
                              hipStream_t stream) {
    const float* S1 = (const float*)d_in[0];
    const float* S2 = (const float*)d_in[1];
    const float* Wq = (const float*)d_in[2];
    const float* Wk = (const float*)d_in[3];
    const float* Wv = (const float*)d_in[4];
    const float* Wo = (const float*)d_in[5];
    const float* bo = (const float*)d_in[6];
    float* Out = (float*)d_out;

    char* ws = (char*)d_ws;
    h_t* S2h  = (h_t*)(ws);                 // 16 MB  (dead after Q-proj)
    h_t* S1h  = (h_t*)(ws + 16777216);      // 16 MB  (dead after Vt-proj)
    h_t* Wqt  = (h_t*)(ws + 33554432);      // 1 MB
    h_t* Wkt  = (h_t*)(ws + 34603008);      // 1 MB
    h_t* Wvot = (h_t*)(ws + 35651584);      // 0.5 MB (dead after Vt-proj)
    h_t* Qh   = (h_t*)(ws + 36175872);      // 32 MB
    h_t* Kh   = (h_t*)(ws + 69730304);      // 32 MB
    h_t* Vt   = (h_t*)(ws + 103284736);     // 16 MB -> end 120,061,952
    // aliases (dead regions reused):
    h_t* Wot  = (h_t*)(ws + 36175872);      // 1 MB  [512][1024] (pre-Qh)
    h_t* Wvh  = (h_t*)(ws + 37224448);      // 1 MB  [512][1024] (pre-Qh)
    h_t* Obar = (h_t*)(ws);                 // 32 MB [2][8][2048][512] over S2h+S1h
    float2* Ml = (float2*)(ws + 35651584);  // 256 KB [2][16384] over Wvot

    k_cast3<<<16896, 256, 0, stream>>>(S1, S2, Wv, S1h, S2h, Wvh);
    k_transpose3<<<dim3(32, 32, 3), 256, 0, stream>>>(Wq, Wk, Wo, Wqt, Wkt, Wot);
    // Wvot[d][c] = sum_e Wot[d][e] * Wvh[c][e] = (Wv @ Wo)^T
    k_gemm<<<dim3(4, 4), 256, 0, stream>>>(Wot, Wvh, Wvot, 512, 512, 1024);
    k_gemm<<<dim3(128, 8), 256, 0, stream>>>(S2h, Wqt, Qh, 16384, 1024, 512);
    k_gemm<<<dim3(128, 8), 256, 0, stream>>>(S1h, Wkt, Kh, 16384, 1024, 512);
    k_gemm_vt<<<dim3(128, 4), 256, 0, stream>>>(S1h, Wvot, bo, Vt, 16384, 512, 512);
    k_attn<<<256, 512, 0, stream>>>(Qh, Kh, Vt, Obar, Ml);
    k_comb<<<8192, 256, 0, stream>>>(Obar, Ml, Out);
}